// Round 12
// baseline (102.953 us; speedup 1.0000x reference)
//
#include <hip/hip_runtime.h>
#include <hip/hip_bf16.h>

#define BATCH  4096
#define INF    1024
#define OUTF   1024
#define KSPL   11
#define KSPB   11264           /* spline K (bytes = elems, i8), k-major   */
#define SW_SCALE 1016.0f       /* 127/0.125 */

using bf16    = __hip_bfloat16;
using short8  = __attribute__((ext_vector_type(8))) short;
using ushort8 = __attribute__((ext_vector_type(8))) unsigned short;
using f32x4   = __attribute__((ext_vector_type(4))) float;
using i32x4   = __attribute__((ext_vector_type(4))) int;
typedef unsigned long long u64;

__device__ __forceinline__ unsigned short f2bf(float f){
  union { float f; unsigned u; } a; a.f = f;
  return (unsigned short)((a.u + 0x7FFFu + ((a.u >> 16) & 1u)) >> 16); // RNE
}

__device__ __forceinline__ void llds16(const void* g, const void* l){
  __builtin_amdgcn_global_load_lds(
      (const __attribute__((address_space(1))) unsigned int*)g,
      (__attribute__((address_space(3))) unsigned int*)l, 16, 0, 0);
}

__device__ __forceinline__ void bar(){
  asm volatile("" ::: "memory");
  __builtin_amdgcn_s_barrier();
  asm volatile("" ::: "memory");
}

__device__ __forceinline__ f32x4 mfma16(short8 a, short8 b, f32x4 c){
  return __builtin_amdgcn_mfma_f32_16x16x32_bf16(a, b, c, 0, 0, 0);
}
__device__ __forceinline__ i32x4 mfma_i8(i32x4 a, i32x4 b, i32x4 c){
  return __builtin_amdgcn_mfma_i32_16x16x64_i8(a, b, c, 0, 0, 0);
}

__device__ __forceinline__ int swz(int L){ return L ^ (((L>>7)&7)<<4); }

// ---------------------------------------------------------------------------
// prep (LDS-free, validated round-9): blocks [0,2048) -> A_sil + A_spl;
// blocks [2048,2560) -> W_b + W_s via in-register transpose.
// Arithmetic identical to rounds 8-11 (absmax bit-identical 0.03125).
// ---------------------------------------------------------------------------
__global__ __launch_bounds__(256) void prep(const float* __restrict__ x,
                                            const float* __restrict__ bw,
                                            const float* __restrict__ sw,
                                            const float* __restrict__ sc,
                                            bf16* __restrict__ A_sil,
                                            char* __restrict__ A_spl,
                                            bf16* __restrict__ W_b,
                                            char* __restrict__ W_s){
  const int t = threadIdx.x;
  if (blockIdx.x < 2048){
    const int gid = blockIdx.x * 256 + t;
    const int b  = gid >> 7;
    const int i0 = (gid & 127) * 8;
    const float* xr = x + (size_t)b * INF + i0;
    f32x4 p0 = *(const f32x4*)xr;
    f32x4 p1 = *(const f32x4*)(xr + 4);
    float v[8];
    #pragma unroll
    for (int j = 0; j < 4; ++j){ v[j] = p0[j]; v[4+j] = p1[j]; }
    ushort8 sl;
    int c[8], q[8];
    #pragma unroll
    for (int j = 0; j < 8; ++j){
      float xx = v[j];
      sl[j] = f2bf(xx / (1.0f + __expf(-xx)));
      float tt = (xx + 1.0f) * 2.5f;
      float fl = floorf(tt);
      c[j] = (int)fl + 3;
      q[j] = (int)rintf(__sinf(3.14159265358979f * (tt - fl)) * 127.0f);
    }
    *(ushort8*)(A_sil + (size_t)b*INF + i0) = sl;
    char* ar = A_spl + (size_t)b * KSPB + i0;
    #pragma unroll
    for (int k = 0; k < KSPL; ++k){
      u64 up = 0;
      #pragma unroll
      for (int j = 0; j < 8; ++j){
        unsigned char byte = (c[j] == k) ? (unsigned char)q[j] : (unsigned char)0;
        up |= ((u64)byte) << (8*j);
      }
      *(u64*)(ar + k*INF) = up;
    }
  } else {
    const int gid = (blockIdx.x - 2048) * 256 + t;
    const int o  = gid >> 7;
    const int i0 = (gid & 127) * 8;
    float buf[88];
    const float* sp = sw + ((size_t)o*INF + i0) * KSPL;
    #pragma unroll
    for (int qd = 0; qd < 22; ++qd)
      ((f32x4*)buf)[qd] = ((const f32x4*)sp)[qd];
    f32x4 c0 = *(const f32x4*)(sc + (size_t)o*INF + i0);
    f32x4 c1 = *(const f32x4*)(sc + (size_t)o*INF + i0 + 4);
    float scv[8];
    #pragma unroll
    for (int j = 0; j < 4; ++j){ scv[j] = c0[j]; scv[4+j] = c1[j]; }
    {
      const float* br = bw + (size_t)o*INF + i0;
      f32x4 v0 = *(const f32x4*)br;
      f32x4 v1 = *(const f32x4*)(br + 4);
      ushort8 u;
      #pragma unroll
      for (int j = 0; j < 4; ++j){ u[j] = f2bf(v0[j]); u[4+j] = f2bf(v1[j]); }
      *(ushort8*)(W_b + (size_t)o*INF + i0) = u;
    }
    char* wr = W_s + (size_t)o * KSPB + i0;
    #pragma unroll
    for (int k = 0; k < KSPL; ++k){
      u64 up = 0;
      #pragma unroll
      for (int j = 0; j < 8; ++j){
        float vv = buf[j*KSPL + k] * scv[j] * SW_SCALE;
        vv = fminf(fmaxf(vv, -127.0f), 127.0f);
        int qq = (int)rintf(vv);
        up |= ((u64)(unsigned char)(signed char)qq) << (8*j);
      }
      *(u64*)(wr + k*INF) = up;
    }
  }
}

// ---------------------------------------------------------------------------
// gemm_i8 (round-12): 8-phase-style fine interleave (m201 port).
// 256x256 tile, BK=64 B, 4 LDS bufs, stage-2-ahead, i16 output.
// Per tile: 4 phases (C-quadrants), each {quadrant ds_reads; 1 staging
// load; bar; setprio; 8 MFMA; setprio; bar}. vmcnt(4) once per tile @P4
// (tail vmcnt(0)) -- load-retirement schedule identical to round-9/11:
// tile t+1's 4 loads (issued during t-1) retired before tile t+1's P1
// reads; buf (t+2)&3 written only after its tile-(t-2) readers' end-bar.
// Mechanism: 2-bar phases let the 2 waves/SIMD run skewed (one in MFMA,
// one draining reads) instead of convoying -- the m218/m201 lever.
// ---------------------------------------------------------------------------
template<int NS>
__global__ __launch_bounds__(512, 2) void gemm_i8k(const char* __restrict__ A,
                                                   const char* __restrict__ W,
                                                   short* __restrict__ Cp){
  constexpr int KSPLIT_B = KSPB / NS;        // 2816
  constexpr int NG       = KSPLIT_B / 64;    // 44
  __shared__ __align__(16) char smem[131072];

  const int bid = blockIdx.x;
  const int xcd = bid & 7, local = bid >> 3;
  const int split = xcd >> 1;
  const int mt    = (xcd & 1) * 8 + (local >> 2);
  const int nt    = local & 3;
  const int bm = mt*256, bn = nt*256;

  const int t    = threadIdx.x;
  const int lane = t & 63, w = t >> 6;
  const int wr = w >> 2, wc = w & 3;
  const int r15 = lane & 15, hi = lane >> 4;

  int offA[8], offB[4];
  #pragma unroll
  for (int m = 0; m < 8; ++m){
    int L = (wr*128 + m*16 + r15)*64 + hi*16;
    offA[m] = swz(L);
  }
  #pragma unroll
  for (int n = 0; n < 4; ++n){
    int L = (wc*64 + n*16 + r15)*64 + hi*16;
    offB[n] = 16384 + swz(L);
  }

  const char* gA[2]; const char* gB[2];
  int ldsA[2], ldsB[2];
  #pragma unroll
  for (int j = 0; j < 2; ++j){
    int P = (t + j*512)*16;
    int L = swz(P);
    int row = L >> 6, inner = L & 63;
    gA[j] = A + (size_t)(bm + row)*KSPB + split*KSPLIT_B + inner;
    gB[j] = W + (size_t)(bn + row)*KSPB + split*KSPLIT_B + inner;
    ldsA[j] = j*8192 + w*1024;
    ldsB[j] = 16384 + j*8192 + w*1024;
  }

  #define STG(j, tile, buf) do{                                              \
    if (j == 0) llds16(gA[0] + (tile)*64, smem + (buf)*32768 + ldsA[0]);     \
    if (j == 1) llds16(gA[1] + (tile)*64, smem + (buf)*32768 + ldsA[1]);     \
    if (j == 2) llds16(gB[0] + (tile)*64, smem + (buf)*32768 + ldsB[0]);     \
    if (j == 3) llds16(gB[1] + (tile)*64, smem + (buf)*32768 + ldsB[1]); }while(0)

  i32x4 acc[8][4] = {};

  // prologue: stage tiles 0,1 (8 loads); retire tile 0; publish
  STG(0,0,0); STG(1,0,0); STG(2,0,0); STG(3,0,0);
  STG(0,1,1); STG(1,1,1); STG(2,1,1); STG(3,1,1);
  asm volatile("s_waitcnt vmcnt(4)" ::: "memory");
  bar();

  #pragma unroll 1
  for (int tt = 0; tt < NG; ++tt){
    const char* bp = smem + (tt&3)*32768;
    const int sb = (tt+2)&3;
    const bool st = (tt+2) < NG;
    i32x4 af[4], ag[4], bf[4];

    // ---- P1: af0-3 + bf0-1; stage load0; MFMA m0-3 x n0-1
    #pragma unroll
    for (int m = 0; m < 4; ++m) af[m] = *(const i32x4*)(bp + offA[m]);
    bf[0] = *(const i32x4*)(bp + offB[0]);
    bf[1] = *(const i32x4*)(bp + offB[1]);
    if (st) STG(0, tt+2, sb);
    bar();
    __builtin_amdgcn_s_setprio(1);
    #pragma unroll
    for (int m = 0; m < 4; ++m){
      acc[m][0] = mfma_i8(af[m], bf[0], acc[m][0]);
      acc[m][1] = mfma_i8(af[m], bf[1], acc[m][1]);
    }
    __builtin_amdgcn_s_setprio(0);
    bar();

    // ---- P2: bf2-3; stage load1; MFMA m0-3 x n2-3
    bf[2] = *(const i32x4*)(bp + offB[2]);
    bf[3] = *(const i32x4*)(bp + offB[3]);
    if (st) STG(1, tt+2, sb);
    bar();
    __builtin_amdgcn_s_setprio(1);
    #pragma unroll
    for (int m = 0; m < 4; ++m){
      acc[m][2] = mfma_i8(af[m], bf[2], acc[m][2]);
      acc[m][3] = mfma_i8(af[m], bf[3], acc[m][3]);
    }
    __builtin_amdgcn_s_setprio(0);
    bar();

    // ---- P3: ag0-3; stage load2; MFMA m4-7 x n0-1
    #pragma unroll
    for (int m = 0; m < 4; ++m) ag[m] = *(const i32x4*)(bp + offA[4+m]);
    if (st) STG(2, tt+2, sb);
    bar();
    __builtin_amdgcn_s_setprio(1);
    #pragma unroll
    for (int m = 0; m < 4; ++m){
      acc[4+m][0] = mfma_i8(ag[m], bf[0], acc[4+m][0]);
      acc[4+m][1] = mfma_i8(ag[m], bf[1], acc[4+m][1]);
    }
    __builtin_amdgcn_s_setprio(0);
    bar();

    // ---- P4: stage load3; counted vmcnt; MFMA m4-7 x n2-3
    if (st) STG(3, tt+2, sb);
    if (st) asm volatile("s_waitcnt vmcnt(4)" ::: "memory");
    else    asm volatile("s_waitcnt vmcnt(0)" ::: "memory");
    bar();
    __builtin_amdgcn_s_setprio(1);
    #pragma unroll
    for (int m = 0; m < 4; ++m){
      acc[4+m][2] = mfma_i8(ag[m], bf[2], acc[4+m][2]);
      acc[4+m][3] = mfma_i8(ag[m], bf[3], acc[4+m][3]);
    }
    __builtin_amdgcn_s_setprio(0);
    bar();
  }
  #undef STG

  short* outp = Cp + (size_t)split * (BATCH*OUTF);
  #pragma unroll
  for (int m = 0; m < 8; ++m){
    const int r0 = bm + wr*128 + m*16 + hi*4;
    #pragma unroll
    for (int n = 0; n < 4; ++n){
      const int cc = bn + wc*64 + n*16 + r15;
      #pragma unroll
      for (int j = 0; j < 4; ++j){
        int v = acc[m][n][j];
        v = (v >  32767) ?  32767 : v;
        v = (v < -32768) ? -32768 : v;
        outp[(size_t)(r0 + j) * OUTF + cc] = (short)v;
      }
    }
  }
}

// ---------------------------------------------------------------------------
// gemm_e (validated): enm = silu(x)@W_b^T (bf16, K=1024, 128x128) with fused
// epilogue out = enm + invP * (Cp0+Cp1+Cp2+Cp3)   [Cp i16].
// ---------------------------------------------------------------------------
__global__ __launch_bounds__(512, 2) void gemm_e(const bf16* __restrict__ A,
                                                 const bf16* __restrict__ W,
                                                 const short* __restrict__ Cp,
                                                 float* __restrict__ out){
  constexpr int NG = 32;
  __shared__ __align__(16) char smem[65536];

  const int bid = blockIdx.x;
  const int fin = (bid & 7) * 32 + (bid >> 3);
  const int mt = fin >> 3, nt = fin & 7;
  const int bm = mt*128, bn = nt*128;

  const int t    = threadIdx.x;
  const int lane = t & 63, w = t >> 6;
  const int wr = w >> 2, wc = w & 3;
  const int r15 = lane & 15, hi = lane >> 4;

  int offA[4], offB[2];
  #pragma unroll
  for (int m = 0; m < 4; ++m){
    int L = (wr*64 + m*16 + r15)*64 + hi*16;
    offA[m] = swz(L);
  }
  #pragma unroll
  for (int n = 0; n < 2; ++n){
    int L = (wc*32 + n*16 + r15)*64 + hi*16;
    offB[n] = 8192 + swz(L);
  }

  const char* gA; const char* gB;
  {
    int P = t*16;
    int L = swz(P);
    int row = L >> 6, inner = L & 63;
    gA = (const char*)A + (size_t)(bm + row)*2048 + inner;
    gB = (const char*)W + (size_t)(bn + row)*2048 + inner;
  }
  const int ldsA = w*1024;
  const int ldsB = 8192 + w*1024;

  #define STAGE(buf, tile) do{ \
    llds16(gA + (tile)*64, smem + (buf)*16384 + ldsA); \
    llds16(gB + (tile)*64, smem + (buf)*16384 + ldsB); }while(0)

  f32x4 acc[4][2] = {};
  short8 afA[4], afB[4], bfA[2], bfB[2];

  STAGE(0,0);
  STAGE(1,1);
  asm volatile("s_waitcnt vmcnt(2)" ::: "memory");
  bar();
  #pragma unroll
  for (int m = 0; m < 4; ++m) afA[m] = *(const short8*)(smem + offA[m]);
  #pragma unroll
  for (int n = 0; n < 2; ++n) bfA[n] = *(const short8*)(smem + offB[n]);

  #define BODY(tt, curA, curB, nxtA, nxtB) do{                                \
    const char* bq_ = smem + (((tt)+1)&3)*16384;                              \
    if ((tt) + 2 < NG){                                                       \
      STAGE(((tt)+2)&3, (tt)+2);                                              \
      asm volatile("s_waitcnt vmcnt(2)" ::: "memory");                        \
    } else {                                                                  \
      asm volatile("s_waitcnt vmcnt(0)" ::: "memory");                        \
    }                                                                         \
    bar();                                                                    \
    __builtin_amdgcn_s_setprio(1);                                            \
    _Pragma("unroll")                                                         \
    for (int m = 0; m < 4; ++m){                                              \
      if ((tt) + 1 < NG){                                                     \
        nxtA[m] = *(const short8*)(bq_ + offA[m]);                            \
        if (m < 2) nxtB[m] = *(const short8*)(bq_ + offB[m]);                 \
      }                                                                       \
      _Pragma("unroll")                                                       \
      for (int n = 0; n < 2; ++n)                                             \
        acc[m][n] = mfma16(curA[m], curB[n], acc[m][n]);                      \
    }                                                                         \
    __builtin_amdgcn_s_setprio(0);                                            \
  }while(0)

  #pragma unroll 1
  for (int s = 0; s < NG/2; ++s){
    BODY(2*s,   afA, bfA, afB, bfB);
    BODY(2*s+1, afB, bfB, afA, bfA);
  }
  #undef BODY
  #undef STAGE

  const float invP = 1.0f / (127.0f * SW_SCALE);
  const size_t NN = (size_t)BATCH * OUTF;
  #pragma unroll
  for (int m = 0; m < 4; ++m){
    const int r0 = bm + wr*64 + m*16 + hi*4;
    #pragma unroll
    for (int n = 0; n < 2; ++n){
      const int cc = bn + wc*32 + n*16 + r15;
      #pragma unroll
      for (int j = 0; j < 4; ++j){
        const size_t idx = (size_t)(r0 + j) * OUTF + cc;
        int s4 = (int)Cp[idx] + (int)Cp[NN + idx]
               + (int)Cp[2*NN + idx] + (int)Cp[3*NN + idx];
        out[idx] = acc[m][n][j] + (float)s4 * invP;
      }
    }
  }
}

// Correct-but-slow safety net if ws_size is tiny.
__global__ __launch_bounds__(256) void fallback(const float* __restrict__ x,
    const float* __restrict__ bw, const float* __restrict__ sw,
    const float* __restrict__ sc, float* __restrict__ out){
  const int b = blockIdx.x, t = threadIdx.x;
  __shared__ float ls[INF], sg[INF];
  __shared__ int   lc[INF];
  for (int i = t; i < INF; i += 256){
    float xx = x[(size_t)b*INF + i];
    ls[i] = xx / (1.0f + __expf(-xx));
    float tt = (xx + 1.0f)*2.5f;
    float fl = floorf(tt);
    int c = (int)fl + 3;
    lc[i] = ((unsigned)c < 11u) ? c : -1;
    sg[i] = __sinf(3.14159265358979f*(tt - fl));
  }
  __syncthreads();
  for (int o = t; o < OUTF; o += 256){
    float acc = 0.f;
    const float* bwr = bw + (size_t)o*INF;
    const float* swr = sw + (size_t)o*INF*KSPL;
    const float* scr = sc + (size_t)o*INF;
    for (int i = 0; i < INF; ++i){
      acc = fmaf(ls[i], bwr[i], acc);
      int c = lc[i];
      if (c >= 0) acc = fmaf(sg[i]*scr[i], swr[i*KSPL + c], acc);
    }
    out[(size_t)b*OUTF + o] = acc;
  }
}

extern "C" void kernel_launch(void* const* d_in, const int* in_sizes, int n_in,
                              void* d_out, int out_size, void* d_ws, size_t ws_size,
                              hipStream_t stream){
  const float* x  = (const float*)d_in[0];
  const float* bw = (const float*)d_in[1];
  const float* sw = (const float*)d_in[2];
  const float* sc = (const float*)d_in[3];
  float* out = (float*)d_out;
  const size_t oAsil = 0;
  const size_t oAspl = oAsil + (size_t)BATCH*INF*2;          //   8.39 MB
  const size_t oWb   = oAspl + (size_t)BATCH*KSPB;           // + 46.14 MB
  const size_t oWs   = oWb   + (size_t)OUTF*INF*2;           // +  2.10 MB
  const size_t oCp   = oWs   + (size_t)OUTF*KSPB;            // + 11.53 MB
  const size_t total = oCp   + (size_t)4*BATCH*OUTF*2;       // + 33.55 MB = 101.7 MB
  if (ws_size >= total){
    bf16*  A_sil = (bf16*)((char*)d_ws + oAsil);
    char*  A_spl = (char*)d_ws + oAspl;
    bf16*  W_b   = (bf16*)((char*)d_ws + oWb);
    char*  W_s   = (char*)d_ws + oWs;
    short* Cp    = (short*)((char*)d_ws + oCp);
    hipLaunchKernelGGL(prep, dim3(2560), dim3(256), 0, stream,
                       x, bw, sw, sc, A_sil, A_spl, W_b, W_s);
    gemm_i8k<4><<<dim3(256), dim3(512), 0, stream>>>(A_spl, W_s, Cp);
    gemm_e<<<dim3(256), dim3(512), 0, stream>>>(A_sil, W_b, Cp, out);
  } else {
    hipLaunchKernelGGL(fallback, dim3(BATCH), dim3(256), 0, stream, x, bw, sw, sc, out);
  }
}

// Round 13
// 95.148 us; speedup vs baseline: 1.0820x; 1.0820x over previous
//
#include <hip/hip_runtime.h>
#include <hip/hip_bf16.h>

#define BATCH  4096
#define INF    1024
#define OUTF   1024
#define KSPL   11
#define KSPB   11264           /* spline K (bytes = elems, i8), k-major   */
#define SW_SCALE 1016.0f       /* 127/0.125 */

using bf16    = __hip_bfloat16;
using short8  = __attribute__((ext_vector_type(8))) short;
using ushort8 = __attribute__((ext_vector_type(8))) unsigned short;
using f32x4   = __attribute__((ext_vector_type(4))) float;
using i32x4   = __attribute__((ext_vector_type(4))) int;
typedef unsigned long long u64;

__device__ __forceinline__ unsigned short f2bf(float f){
  union { float f; unsigned u; } a; a.f = f;
  return (unsigned short)((a.u + 0x7FFFu + ((a.u >> 16) & 1u)) >> 16); // RNE
}

__device__ __forceinline__ void llds16(const void* g, const void* l){
  __builtin_amdgcn_global_load_lds(
      (const __attribute__((address_space(1))) unsigned int*)g,
      (__attribute__((address_space(3))) unsigned int*)l, 16, 0, 0);
}

__device__ __forceinline__ void bar(){
  asm volatile("" ::: "memory");
  __builtin_amdgcn_s_barrier();
  asm volatile("" ::: "memory");
}

__device__ __forceinline__ f32x4 mfma16(short8 a, short8 b, f32x4 c){
  return __builtin_amdgcn_mfma_f32_16x16x32_bf16(a, b, c, 0, 0, 0);
}
__device__ __forceinline__ i32x4 mfma_i8(i32x4 a, i32x4 b, i32x4 c){
  return __builtin_amdgcn_mfma_i32_16x16x64_i8(a, b, c, 0, 0, 0);
}

__device__ __forceinline__ int swz(int L){ return L ^ (((L>>7)&7)<<4); }

// ---------------------------------------------------------------------------
// prep (LDS-free, validated round-9): blocks [0,2048) -> A_sil + A_spl;
// blocks [2048,2560) -> W_b + W_s via in-register transpose.
// Arithmetic identical to rounds 8-12 (absmax bit-identical 0.03125).
// ---------------------------------------------------------------------------
__global__ __launch_bounds__(256) void prep(const float* __restrict__ x,
                                            const float* __restrict__ bw,
                                            const float* __restrict__ sw,
                                            const float* __restrict__ sc,
                                            bf16* __restrict__ A_sil,
                                            char* __restrict__ A_spl,
                                            bf16* __restrict__ W_b,
                                            char* __restrict__ W_s){
  const int t = threadIdx.x;
  if (blockIdx.x < 2048){
    const int gid = blockIdx.x * 256 + t;
    const int b  = gid >> 7;
    const int i0 = (gid & 127) * 8;
    const float* xr = x + (size_t)b * INF + i0;
    f32x4 p0 = *(const f32x4*)xr;
    f32x4 p1 = *(const f32x4*)(xr + 4);
    float v[8];
    #pragma unroll
    for (int j = 0; j < 4; ++j){ v[j] = p0[j]; v[4+j] = p1[j]; }
    ushort8 sl;
    int c[8], q[8];
    #pragma unroll
    for (int j = 0; j < 8; ++j){
      float xx = v[j];
      sl[j] = f2bf(xx / (1.0f + __expf(-xx)));
      float tt = (xx + 1.0f) * 2.5f;
      float fl = floorf(tt);
      c[j] = (int)fl + 3;
      q[j] = (int)rintf(__sinf(3.14159265358979f * (tt - fl)) * 127.0f);
    }
    *(ushort8*)(A_sil + (size_t)b*INF + i0) = sl;
    char* ar = A_spl + (size_t)b * KSPB + i0;
    #pragma unroll
    for (int k = 0; k < KSPL; ++k){
      u64 up = 0;
      #pragma unroll
      for (int j = 0; j < 8; ++j){
        unsigned char byte = (c[j] == k) ? (unsigned char)q[j] : (unsigned char)0;
        up |= ((u64)byte) << (8*j);
      }
      *(u64*)(ar + k*INF) = up;
    }
  } else {
    const int gid = (blockIdx.x - 2048) * 256 + t;
    const int o  = gid >> 7;
    const int i0 = (gid & 127) * 8;
    float buf[88];
    const float* sp = sw + ((size_t)o*INF + i0) * KSPL;
    #pragma unroll
    for (int qd = 0; qd < 22; ++qd)
      ((f32x4*)buf)[qd] = ((const f32x4*)sp)[qd];
    f32x4 c0 = *(const f32x4*)(sc + (size_t)o*INF + i0);
    f32x4 c1 = *(const f32x4*)(sc + (size_t)o*INF + i0 + 4);
    float scv[8];
    #pragma unroll
    for (int j = 0; j < 4; ++j){ scv[j] = c0[j]; scv[4+j] = c1[j]; }
    {
      const float* br = bw + (size_t)o*INF + i0;
      f32x4 v0 = *(const f32x4*)br;
      f32x4 v1 = *(const f32x4*)(br + 4);
      ushort8 u;
      #pragma unroll
      for (int j = 0; j < 4; ++j){ u[j] = f2bf(v0[j]); u[4+j] = f2bf(v1[j]); }
      *(ushort8*)(W_b + (size_t)o*INF + i0) = u;
    }
    char* wr = W_s + (size_t)o * KSPB + i0;
    #pragma unroll
    for (int k = 0; k < KSPL; ++k){
      u64 up = 0;
      #pragma unroll
      for (int j = 0; j < 8; ++j){
        float vv = buf[j*KSPL + k] * scv[j] * SW_SCALE;
        vv = fminf(fmaxf(vv, -127.0f), 127.0f);
        int qq = (int)rintf(vv);
        up |= ((u64)(unsigned char)(signed char)qq) << (8*j);
      }
      *(u64*)(wr + k*INF) = up;
    }
  }
}

// ---------------------------------------------------------------------------
// gemm_i8 (round-11 verbatim, best measured 45.6us): Cp[split] = A_spl@W_s^T.
// 256x256 tile, BK=64 B, 4 LDS bufs, full register cross-tile pipeline,
// 0-conflict swizzle, NS=4 XCD-L2 mapping, T5 setprio, i16 partials.
// ---------------------------------------------------------------------------
template<int NS>
__global__ __launch_bounds__(512, 2) void gemm_i8k(const char* __restrict__ A,
                                                   const char* __restrict__ W,
                                                   short* __restrict__ Cp){
  constexpr int KSPLIT_B = KSPB / NS;        // 2816
  constexpr int NG       = KSPLIT_B / 64;    // 44
  __shared__ __align__(16) char smem[131072];

  const int bid = blockIdx.x;
  const int xcd = bid & 7, local = bid >> 3;
  const int split = xcd >> 1;
  const int mt    = (xcd & 1) * 8 + (local >> 2);
  const int nt    = local & 3;
  const int bm = mt*256, bn = nt*256;

  const int t    = threadIdx.x;
  const int lane = t & 63, w = t >> 6;
  const int wr = w >> 2, wc = w & 3;
  const int r15 = lane & 15, hi = lane >> 4;

  int offA[8], offB[4];
  #pragma unroll
  for (int m = 0; m < 8; ++m){
    int L = (wr*128 + m*16 + r15)*64 + hi*16;
    offA[m] = swz(L);
  }
  #pragma unroll
  for (int n = 0; n < 4; ++n){
    int L = (wc*64 + n*16 + r15)*64 + hi*16;
    offB[n] = 16384 + swz(L);
  }

  const char* gA[2]; const char* gB[2];
  int ldsA[2], ldsB[2];
  #pragma unroll
  for (int j = 0; j < 2; ++j){
    int P = (t + j*512)*16;
    int L = swz(P);
    int row = L >> 6, inner = L & 63;
    gA[j] = A + (size_t)(bm + row)*KSPB + split*KSPLIT_B + inner;
    gB[j] = W + (size_t)(bn + row)*KSPB + split*KSPLIT_B + inner;
    ldsA[j] = j*8192 + w*1024;
    ldsB[j] = 16384 + j*8192 + w*1024;
  }

  #define STAGE(buf, tile) do{ \
    llds16(gA[0] + (tile)*64, smem + (buf)*32768 + ldsA[0]); \
    llds16(gA[1] + (tile)*64, smem + (buf)*32768 + ldsA[1]); \
    llds16(gB[0] + (tile)*64, smem + (buf)*32768 + ldsB[0]); \
    llds16(gB[1] + (tile)*64, smem + (buf)*32768 + ldsB[1]); }while(0)

  i32x4 acc[8][4] = {};
  i32x4 afA[4], afB[4], bfA[4], bfB[4];

  STAGE(0,0);
  STAGE(1,1);
  asm volatile("s_waitcnt vmcnt(4)" ::: "memory");
  bar();
  #pragma unroll
  for (int n = 0; n < 4; ++n) bfA[n] = *(const i32x4*)(smem + offB[n]);
  #pragma unroll
  for (int m = 0; m < 4; ++m) afA[m] = *(const i32x4*)(smem + offA[m]);

  #define BODY(tt, curA, curB, nxtA, nxtB) do{                                \
    const char* bp_ = smem + ((tt)&3)*32768;                                  \
    const char* bq_ = smem + (((tt)+1)&3)*32768;                              \
    if ((tt) + 2 < NG){                                                       \
      STAGE(((tt)+2)&3, (tt)+2);                                              \
      asm volatile("s_waitcnt vmcnt(4)" ::: "memory");                        \
    } else {                                                                  \
      asm volatile("s_waitcnt vmcnt(0)" ::: "memory");                        \
    }                                                                         \
    bar();                                                                    \
    i32x4 ag_[4];                                                             \
    __builtin_amdgcn_s_setprio(1);                                            \
    _Pragma("unroll")                                                         \
    for (int m = 0; m < 4; ++m){                                              \
      ag_[m] = *(const i32x4*)(bp_ + offA[4+m]);                              \
      _Pragma("unroll")                                                       \
      for (int n = 0; n < 4; ++n)                                             \
        acc[m][n] = mfma_i8(curA[m], curB[n], acc[m][n]);                     \
    }                                                                         \
    _Pragma("unroll")                                                         \
    for (int m = 0; m < 4; ++m){                                              \
      if ((tt) + 1 < NG){                                                     \
        nxtA[m] = *(const i32x4*)(bq_ + offA[m]);                             \
        nxtB[m] = *(const i32x4*)(bq_ + offB[m]);                             \
      }                                                                       \
      _Pragma("unroll")                                                       \
      for (int n = 0; n < 4; ++n)                                             \
        acc[4+m][n] = mfma_i8(ag_[m], curB[n], acc[4+m][n]);                  \
    }                                                                         \
    __builtin_amdgcn_s_setprio(0);                                            \
  }while(0)

  #pragma unroll 1
  for (int s = 0; s < NG/2; ++s){
    BODY(2*s,   afA, bfA, afB, bfB);
    BODY(2*s+1, afB, bfB, afA, bfA);
  }
  #undef BODY
  #undef STAGE

  short* outp = Cp + (size_t)split * (BATCH*OUTF);
  #pragma unroll
  for (int m = 0; m < 8; ++m){
    const int r0 = bm + wr*128 + m*16 + hi*4;
    #pragma unroll
    for (int n = 0; n < 4; ++n){
      const int cc = bn + wc*64 + n*16 + r15;
      #pragma unroll
      for (int j = 0; j < 4; ++j){
        int v = acc[m][n][j];
        v = (v >  32767) ?  32767 : v;
        v = (v < -32768) ? -32768 : v;
        outp[(size_t)(r0 + j) * OUTF + cc] = (short)v;
      }
    }
  }
}

// ---------------------------------------------------------------------------
// gemm_e (round-13): enm = silu(x)@W_b^T (bf16, K=1024, 128x128) with fused
// epilogue out = enm + invP * (Cp0+Cp1+Cp2+Cp3)  [Cp i16].
// Change vs r11: 3 LDS bufs x 16 KB = 48 KB (was 64 KB) -> 2+ blocks/CU
// co-resident for cross-block MFMA/LDS overlap. 3-buf proof (as r10):
// STAGE(t+2)->buf (t+2)%3=(t-1)%3, readers(t-1) done at bar(t-1); vmcnt(2)
// at iter t retires t+1's loads before its preloads (issued after bar).
// ---------------------------------------------------------------------------
__global__ __launch_bounds__(512, 2) void gemm_e(const bf16* __restrict__ A,
                                                 const bf16* __restrict__ W,
                                                 const short* __restrict__ Cp,
                                                 float* __restrict__ out){
  constexpr int NG = 32;
  __shared__ __align__(16) char smem[49152];   // 3 bufs x 16 KB

  const int bid = blockIdx.x;
  const int fin = (bid & 7) * 32 + (bid >> 3);
  const int mt = fin >> 3, nt = fin & 7;
  const int bm = mt*128, bn = nt*128;

  const int t    = threadIdx.x;
  const int lane = t & 63, w = t >> 6;
  const int wr = w >> 2, wc = w & 3;
  const int r15 = lane & 15, hi = lane >> 4;

  int offA[4], offB[2];
  #pragma unroll
  for (int m = 0; m < 4; ++m){
    int L = (wr*64 + m*16 + r15)*64 + hi*16;
    offA[m] = swz(L);
  }
  #pragma unroll
  for (int n = 0; n < 2; ++n){
    int L = (wc*32 + n*16 + r15)*64 + hi*16;
    offB[n] = 8192 + swz(L);
  }

  const char* gA; const char* gB;
  {
    int P = t*16;
    int L = swz(P);
    int row = L >> 6, inner = L & 63;
    gA = (const char*)A + (size_t)(bm + row)*2048 + inner;
    gB = (const char*)W + (size_t)(bn + row)*2048 + inner;
  }
  const int ldsA = w*1024;
  const int ldsB = 8192 + w*1024;

  #define STAGE(buf, tile) do{ \
    llds16(gA + (tile)*64, smem + (buf)*16384 + ldsA); \
    llds16(gB + (tile)*64, smem + (buf)*16384 + ldsB); }while(0)

  f32x4 acc[4][2] = {};
  short8 afA[4], afB[4], bfA[2], bfB[2];

  STAGE(0,0);
  STAGE(1,1);
  asm volatile("s_waitcnt vmcnt(2)" ::: "memory");
  bar();
  #pragma unroll
  for (int m = 0; m < 4; ++m) afA[m] = *(const short8*)(smem + offA[m]);
  #pragma unroll
  for (int n = 0; n < 2; ++n) bfA[n] = *(const short8*)(smem + offB[n]);

  #define BODY(tt, curA, curB, nxtA, nxtB) do{                                \
    int nb_ = ((tt)+1) % 3;                                                   \
    const char* bq_ = smem + nb_*16384;                                       \
    if ((tt) + 2 < NG){                                                       \
      STAGE(((tt)+2) % 3, (tt)+2);                                            \
      asm volatile("s_waitcnt vmcnt(2)" ::: "memory");                        \
    } else {                                                                  \
      asm volatile("s_waitcnt vmcnt(0)" ::: "memory");                        \
    }                                                                         \
    bar();                                                                    \
    __builtin_amdgcn_s_setprio(1);                                            \
    _Pragma("unroll")                                                         \
    for (int m = 0; m < 4; ++m){                                              \
      if ((tt) + 1 < NG){                                                     \
        nxtA[m] = *(const short8*)(bq_ + offA[m]);                            \
        if (m < 2) nxtB[m] = *(const short8*)(bq_ + offB[m]);                 \
      }                                                                       \
      _Pragma("unroll")                                                       \
      for (int n = 0; n < 2; ++n)                                             \
        acc[m][n] = mfma16(curA[m], curB[n], acc[m][n]);                      \
    }                                                                         \
    __builtin_amdgcn_s_setprio(0);                                            \
  }while(0)

  #pragma unroll 1
  for (int s = 0; s < NG/2; ++s){
    BODY(2*s,   afA, bfA, afB, bfB);
    BODY(2*s+1, afB, bfB, afA, bfA);
  }
  #undef BODY
  #undef STAGE

  const float invP = 1.0f / (127.0f * SW_SCALE);
  const size_t NN = (size_t)BATCH * OUTF;
  #pragma unroll
  for (int m = 0; m < 4; ++m){
    const int r0 = bm + wr*64 + m*16 + hi*4;
    #pragma unroll
    for (int n = 0; n < 2; ++n){
      const int cc = bn + wc*32 + n*16 + r15;
      #pragma unroll
      for (int j = 0; j < 4; ++j){
        const size_t idx = (size_t)(r0 + j) * OUTF + cc;
        int s4 = (int)Cp[idx] + (int)Cp[NN + idx]
               + (int)Cp[2*NN + idx] + (int)Cp[3*NN + idx];
        out[idx] = acc[m][n][j] + (float)s4 * invP;
      }
    }
  }
}

// Correct-but-slow safety net if ws_size is tiny.
__global__ __launch_bounds__(256) void fallback(const float* __restrict__ x,
    const float* __restrict__ bw, const float* __restrict__ sw,
    const float* __restrict__ sc, float* __restrict__ out){
  const int b = blockIdx.x, t = threadIdx.x;
  __shared__ float ls[INF], sg[INF];
  __shared__ int   lc[INF];
  for (int i = t; i < INF; i += 256){
    float xx = x[(size_t)b*INF + i];
    ls[i] = xx / (1.0f + __expf(-xx));
    float tt = (xx + 1.0f)*2.5f;
    float fl = floorf(tt);
    int c = (int)fl + 3;
    lc[i] = ((unsigned)c < 11u) ? c : -1;
    sg[i] = __sinf(3.14159265358979f*(tt - fl));
  }
  __syncthreads();
  for (int o = t; o < OUTF; o += 256){
    float acc = 0.f;
    const float* bwr = bw + (size_t)o*INF;
    const float* swr = sw + (size_t)o*INF*KSPL;
    const float* scr = sc + (size_t)o*INF;
    for (int i = 0; i < INF; ++i){
      acc = fmaf(ls[i], bwr[i], acc);
      int c = lc[i];
      if (c >= 0) acc = fmaf(sg[i]*scr[i], swr[i*KSPL + c], acc);
    }
    out[(size_t)b*OUTF + o] = acc;
  }
}

extern "C" void kernel_launch(void* const* d_in, const int* in_sizes, int n_in,
                              void* d_out, int out_size, void* d_ws, size_t ws_size,
                              hipStream_t stream){
  const float* x  = (const float*)d_in[0];
  const float* bw = (const float*)d_in[1];
  const float* sw = (const float*)d_in[2];
  const float* sc = (const float*)d_in[3];
  float* out = (float*)d_out;
  const size_t oAsil = 0;
  const size_t oAspl = oAsil + (size_t)BATCH*INF*2;          //   8.39 MB
  const size_t oWb   = oAspl + (size_t)BATCH*KSPB;           // + 46.14 MB
  const size_t oWs   = oWb   + (size_t)OUTF*INF*2;           // +  2.10 MB
  const size_t oCp   = oWs   + (size_t)OUTF*KSPB;            // + 11.53 MB
  const size_t total = oCp   + (size_t)4*BATCH*OUTF*2;       // + 33.55 MB = 101.7 MB
  if (ws_size >= total){
    bf16*  A_sil = (bf16*)((char*)d_ws + oAsil);
    char*  A_spl = (char*)d_ws + oAspl;
    bf16*  W_b   = (bf16*)((char*)d_ws + oWb);
    char*  W_s   = (char*)d_ws + oWs;
    short* Cp    = (short*)((char*)d_ws + oCp);
    hipLaunchKernelGGL(prep, dim3(2560), dim3(256), 0, stream,
                       x, bw, sw, sc, A_sil, A_spl, W_b, W_s);
    gemm_i8k<4><<<dim3(256), dim3(512), 0, stream>>>(A_spl, W_s, Cp);
    gemm_e<<<dim3(256), dim3(512), 0, stream>>>(A_sil, W_b, Cp, out);
  } else {
    hipLaunchKernelGGL(fallback, dim3(BATCH), dim3(256), 0, stream, x, bw, sw, sc, out);
  }
}